// Round 1
// 191.677 us; speedup vs baseline: 1.0078x; 1.0078x over previous
//
#include <hip/hip_runtime.h>
#include <hip/hip_bf16.h>

typedef __bf16 bf16;
typedef __bf16 bf16x4 __attribute__((ext_vector_type(4)));
typedef __bf16 bf16x8 __attribute__((ext_vector_type(8)));
typedef float floatx4 __attribute__((ext_vector_type(4)));

#define MFMA_16x16x32(a, b, c) __builtin_amdgcn_mfma_f32_16x16x32_bf16((a), (b), (c), 0, 0, 0)
#define NEG_INF (-__builtin_inff())

// Problem constants (B=2, S=2048, D=1024, H=16, d=64)
#define CB 2
#define CS 2048
#define CD 1024
#define CH 16
#define CM (CB * CS)
// Q prescale: DIM^-0.5 * log2(e)  (softmax done in base-2 domain)
#define QSC (0.03125f * 1.44269504088896340736f)

// async global->LDS, 16B per lane; LDS dest = wave-uniform base + lane*16
__device__ __forceinline__ void async16(const bf16* g, bf16* l) {
    __builtin_amdgcn_global_load_lds(
        (const __attribute__((address_space(1))) void*)g,
        (__attribute__((address_space(3))) void*)l, 16, 0, 0);
}

// ---------------------------------------------------------------------------
// Prep: x fp32 -> bf16
// ---------------------------------------------------------------------------
__global__ __launch_bounds__(256) void conv_x(const float* __restrict__ x,
                                              bf16* __restrict__ xb) {
    size_t i = ((size_t)blockIdx.x * 256 + threadIdx.x) * 8;
    float4 a = *(const float4*)(x + i);
    float4 b = *(const float4*)(x + i + 4);
    bf16x8 v;
    v[0] = (bf16)a.x; v[1] = (bf16)a.y; v[2] = (bf16)a.z; v[3] = (bf16)a.w;
    v[4] = (bf16)b.x; v[5] = (bf16)b.y; v[6] = (bf16)b.z; v[7] = (bf16)b.w;
    *(bf16x8*)(xb + i) = v;
}

// ---------------------------------------------------------------------------
// Prep: W [K][N] fp32 -> Wt [N][K] bf16 (64x64 LDS tile transpose)
// grid: (N/64, K/64, 4)  — z selects which W
// ---------------------------------------------------------------------------
__global__ __launch_bounds__(256) void conv_wt(
    const float* __restrict__ W0, const float* __restrict__ W1,
    const float* __restrict__ W2, const float* __restrict__ W3,
    bf16* __restrict__ Wt) {
    __shared__ bf16 Ws[64 * 68];
    const float* W = blockIdx.z == 0 ? W0 : blockIdx.z == 1 ? W1
                   : blockIdx.z == 2 ? W2 : W3;
    bf16* out = Wt + (size_t)blockIdx.z * CD * CD;
    const int t = threadIdx.x;
    const int n0 = blockIdx.x * 64, k0 = blockIdx.y * 64;
    const int rr = t >> 4, c4 = (t & 15) * 4;
#pragma unroll
    for (int i = 0; i < 4; i++) {
        int r = rr + i * 16;
        float4 f = *(const float4*)(W + (size_t)(k0 + r) * CD + n0 + c4);
        bf16x4 v;
        v[0] = (bf16)f.x; v[1] = (bf16)f.y; v[2] = (bf16)f.z; v[3] = (bf16)f.w;
        *(bf16x4*)&Ws[r * 68 + c4] = v;
    }
    __syncthreads();
#pragma unroll
    for (int i = 0; i < 4; i++) {
        int n = rr + i * 16;
        bf16x4 v;
#pragma unroll
        for (int j = 0; j < 4; j++) v[j] = Ws[(c4 + j) * 68 + n];
        *(bf16x4*)(out + (size_t)(n0 + n) * CD + k0 + c4) = v;
    }
}

// ---------------------------------------------------------------------------
// Fused QKV GEMM (m97 structure): 128x128 tile, BK=32, global_load_lds x16B.
// which = blockIdx.x>>3: 0->Q (scaled by QSC, [bh][S][64]), 1->K ([bh][S][64]),
// 2->V (transposed store [bh][64][S], packed bf16x4 along tokens).
// ---------------------------------------------------------------------------
__global__ __launch_bounds__(256) void gemm_qkv(
    const bf16* __restrict__ A, const bf16* __restrict__ Bt,
    const float* __restrict__ bq, const float* __restrict__ bk,
    const float* __restrict__ bv,
    bf16* __restrict__ Qb, bf16* __restrict__ Kb, bf16* __restrict__ Vb) {
    __shared__ bf16 As[128 * 32];
    __shared__ bf16 Bs[128 * 32];
    const int t = threadIdx.x, w = t >> 6, lane = t & 63;
    const int quad = lane >> 4, l15 = lane & 15;
    const int which = blockIdx.x >> 3;
    const int bn = (blockIdx.x & 7) * 128, bm = blockIdx.y * 128;
    const bf16* Bw = Bt + (size_t)which * CD * CD;

    const bf16* ag = A + (size_t)(bm + w * 16 + (lane >> 2)) * CD + (lane & 3) * 8;
    const bf16* bg = Bw + (size_t)(bn + w * 16 + (lane >> 2)) * CD + (lane & 3) * 8;
    const int lo = w * 16 * 32;   // wave-uniform LDS chunk base

    const int wm = (w >> 1) * 64, wn = (w & 1) * 64;
    floatx4 acc[4][4] = {};

    for (int k0 = 0; k0 < CD; k0 += 32) {
        async16(ag + k0, &As[lo]);
        async16(ag + (size_t)64 * CD + k0, &As[lo + 64 * 32]);
        async16(bg + k0, &Bs[lo]);
        async16(bg + (size_t)64 * CD + k0, &Bs[lo + 64 * 32]);
        __syncthreads();
        bf16x8 af[4], bfr[4];
#pragma unroll
        for (int mt = 0; mt < 4; mt++)
            af[mt] = *(const bf16x8*)&As[(wm + mt * 16 + l15) * 32 + quad * 8];
#pragma unroll
        for (int nt = 0; nt < 4; nt++)
            bfr[nt] = *(const bf16x8*)&Bs[(wn + nt * 16 + l15) * 32 + quad * 8];
#pragma unroll
        for (int mt = 0; mt < 4; mt++)
#pragma unroll
            for (int nt = 0; nt < 4; nt++)
                acc[mt][nt] = MFMA_16x16x32(af[mt], bfr[nt], acc[mt][nt]);
        __syncthreads();
    }

    const float* bias = which == 0 ? bq : which == 1 ? bk : bv;
    bf16* out = which == 0 ? Qb : Kb;
#pragma unroll
    for (int mt = 0; mt < 4; mt++) {
#pragma unroll
        for (int nt = 0; nt < 4; nt++) {
            int token = bm + wm + mt * 16 + quad * 4;      // 4 consecutive tokens
            int col = bn + wn + nt * 16 + l15;             // feature
            int b = token >> 11, s = token & (CS - 1);
            int h = col >> 6, dd = col & 63;
            if (which == 2) {
                // V^T [bh][d][S]: 4 tokens contiguous -> packed 8B store
                bf16x4 pv;
#pragma unroll
                for (int r = 0; r < 4; r++) pv[r] = (bf16)(acc[mt][nt][r] + bias[col]);
                *(bf16x4*)&Vb[(((size_t)(b * CH + h)) * 64 + dd) * CS + s] = pv;
            } else {
#pragma unroll
                for (int r = 0; r < 4; r++) {
                    float v = acc[mt][nt][r] + bias[col];
                    if (which == 0) v *= QSC;
                    out[(((size_t)(b * CH + h)) * CS + s + r) * 64 + dd] = (bf16)v;
                }
            }
        }
    }
}

// ---------------------------------------------------------------------------
// O-projection GEMM: 64x128 tile, fp32 output. grid: (8, M/64).
// ---------------------------------------------------------------------------
__global__ __launch_bounds__(256) void gemm_o(
    const bf16* __restrict__ A, const bf16* __restrict__ Bt,
    const float* __restrict__ bias, float* __restrict__ out) {
    __shared__ bf16 As[64 * 32];
    __shared__ bf16 Bs[128 * 32];
    const int t = threadIdx.x, w = t >> 6, lane = t & 63;
    const int quad = lane >> 4, l15 = lane & 15;
    const int bn = blockIdx.x * 128, bm = blockIdx.y * 64;

    const bf16* ag = A + (size_t)(bm + w * 16 + (lane >> 2)) * CD + (lane & 3) * 8;
    const bf16* bg = Bt + (size_t)(bn + w * 16 + (lane >> 2)) * CD + (lane & 3) * 8;
    const int lo = w * 16 * 32;

    const int wm = (w >> 1) * 32, wn = (w & 1) * 64;
    floatx4 acc[2][4] = {};

    for (int k0 = 0; k0 < CD; k0 += 32) {
        async16(ag + k0, &As[lo]);
        async16(bg + k0, &Bs[lo]);
        async16(bg + (size_t)64 * CD + k0, &Bs[lo + 64 * 32]);
        __syncthreads();
        bf16x8 af[2], bfr[4];
#pragma unroll
        for (int mt = 0; mt < 2; mt++)
            af[mt] = *(const bf16x8*)&As[(wm + mt * 16 + l15) * 32 + quad * 8];
#pragma unroll
        for (int nt = 0; nt < 4; nt++)
            bfr[nt] = *(const bf16x8*)&Bs[(wn + nt * 16 + l15) * 32 + quad * 8];
#pragma unroll
        for (int mt = 0; mt < 2; mt++)
#pragma unroll
            for (int nt = 0; nt < 4; nt++)
                acc[mt][nt] = MFMA_16x16x32(af[mt], bfr[nt], acc[mt][nt]);
        __syncthreads();
    }

#pragma unroll
    for (int mt = 0; mt < 2; mt++)
#pragma unroll
        for (int nt = 0; nt < 4; nt++)
#pragma unroll
            for (int r = 0; r < 4; r++) {
                int row = bm + wm + mt * 16 + quad * 4 + r;
                int col = bn + wn + nt * 16 + l15;
                out[(size_t)row * CD + col] = acc[mt][nt][r] + bias[col];
            }
}

// ---------------------------------------------------------------------------
// Flash attention v6 — v5 + {double-buffered K/V LDS (1 barrier/tile),
// defer-max rescale (THR=8 log2), per-lane l partials, s_setprio on MFMA}.
// Transposed score scheme: S^T = K·Q^T so qrow = lane (l15); P^T via LDS.
// Block = 256 thr = 128 qrows; 64-key tiles; 2-deep global->reg prefetch.
// Grid 512 = 32 bh x 16 q-blocks; first 256 blocks = long halves (qb 15..8),
// next 256 = short (qb 0..7) so round-robin placement pairs long+short per CU.
// ---------------------------------------------------------------------------
__global__ __launch_bounds__(256) void attn_kernel(
    const bf16* __restrict__ Q, const bf16* __restrict__ Kg,
    const bf16* __restrict__ Vg, bf16* __restrict__ Ob) {
    __shared__ bf16 Ks[2][64 * 72];   // [buf][key][dim]
    __shared__ bf16 Vt[2][64 * 72];   // [buf][dim][key]
    __shared__ bf16 Pt[4][32 * 72];   // per-wave P^T as [qrow][key]

    const int t = threadIdx.x;
    const int w = t >> 6, lane = t & 63;
    const int quad = lane >> 4, l15 = lane & 15;

    const int half = blockIdx.x >> 8;        // 0: long q-blocks, 1: short
    const int slot = blockIdx.x & 255;
    const int bh   = slot & 31;              // B*H = 32
    const int qq   = slot >> 5;              // 0..7
    const int qb   = half ? qq : (15 - qq);  // q-block (128 rows) 0..15
    const int q0   = qb * 128;
    const int wrow0 = q0 + w * 32;           // this wave's first qrow
    const int nT = 2 * qb + 2;               // 64-key tiles (always >= 2)

    const bf16* Qh = Q + (size_t)bh * CS * 64;
    const bf16* Kh = Kg + (size_t)bh * CS * 64;
    const bf16* Vh = Vg + (size_t)bh * 64 * CS;

    // staging map: thread covers 16B x2 of one K row and one V^T row
    const int strow = t >> 2, soff = (t & 3) * 16;
    const bf16* ksrc = Kh + (size_t)strow * 64 + soff;   // + kt*64*64
    const bf16* vsrc = Vh + (size_t)strow * CS + soff;   // + kt*64
    const int sbase = strow * 72 + soff;

    // ---- tile 0: regs -> LDS buf 0 (visible after first barrier)
    bf16x8 kr0 = *(const bf16x8*)ksrc;
    bf16x8 kr1 = *(const bf16x8*)(ksrc + 8);
    bf16x8 vr0 = *(const bf16x8*)vsrc;
    bf16x8 vr1 = *(const bf16x8*)(vsrc + 8);
    *(bf16x8*)&Ks[0][sbase]     = kr0;
    *(bf16x8*)&Ks[0][sbase + 8] = kr1;
    *(bf16x8*)&Vt[0][sbase]     = vr0;
    *(bf16x8*)&Vt[0][sbase + 8] = vr1;
    // ---- prefetch tile 1 into regs (nT >= 2 always)
    kr0 = *(const bf16x8*)(ksrc + 64 * 64);
    kr1 = *(const bf16x8*)(ksrc + 64 * 64 + 8);
    vr0 = *(const bf16x8*)(vsrc + 64);
    vr1 = *(const bf16x8*)(vsrc + 64 + 8);

    // ---- Q fragments (B-operand of S^T): Q[qrow=g*16+l15][dim=quad*8+j+32c]
    bf16x8 qf[2][2];
#pragma unroll
    for (int g = 0; g < 2; g++) {
        const bf16* qsrc = Qh + (size_t)(wrow0 + g * 16 + l15) * 64 + quad * 8;
        qf[g][0] = *(const bf16x8*)qsrc;
        qf[g][1] = *(const bf16x8*)(qsrc + 32);
    }

    floatx4 o[4][2] = {};        // O^T: [dim-subtile][qrow-group]
    float m_r[2] = {NEG_INF, NEG_INF};
    float l_r[2] = {0.f, 0.f};   // per-lane partial row-sums (reduced at end)

    bf16* pw = Pt[w];

    for (int kt = 0; kt < nT; kt++) {
        const int cur = kt & 1;
        const int ks0 = kt * 64;
        __syncthreads();   // buf[cur] staged; buf[cur^1] readers done

        // ---- stage tile kt+1 into the other buffer (regs loaded last window)
        *(bf16x8*)&Ks[cur ^ 1][sbase]     = kr0;
        *(bf16x8*)&Ks[cur ^ 1][sbase + 8] = kr1;
        *(bf16x8*)&Vt[cur ^ 1][sbase]     = vr0;
        *(bf16x8*)&Vt[cur ^ 1][sbase + 8] = vr1;
        // ---- issue global loads for tile kt+2 (latency hidden by compute)
        {
            int nk = (kt + 2 < nT) ? kt + 2 : 0;
            const bf16* kn = ksrc + (size_t)nk * 64 * 64;
            const bf16* vn = vsrc + nk * 64;
            kr0 = *(const bf16x8*)kn;
            kr1 = *(const bf16x8*)(kn + 8);
            vr0 = *(const bf16x8*)vn;
            vr1 = *(const bf16x8*)(vn + 8);
        }
        // waves whose rows are all below this key tile skip compute
        if (ks0 > wrow0 + 31) continue;

        const bf16* ksb = Ks[cur];
        const bf16* vtb = Vt[cur];

        // ---- S^T = K·Q^T: lane holds S^T[key=nt*16+quad*4+r][qrow=g*16+l15]
        floatx4 sc[2][4] = {};
        __builtin_amdgcn_s_setprio(1);
#pragma unroll
        for (int nt = 0; nt < 4; nt++) {
            bf16x8 af0 = *(const bf16x8*)&ksb[(nt * 16 + l15) * 72 + quad * 8];
            bf16x8 af1 = *(const bf16x8*)&ksb[(nt * 16 + l15) * 72 + 32 + quad * 8];
#pragma unroll
            for (int g = 0; g < 2; g++) {
                sc[g][nt] = MFMA_16x16x32(af0, qf[g][0], sc[g][nt]);
                sc[g][nt] = MFMA_16x16x32(af1, qf[g][1], sc[g][nt]);
            }
        }
        __builtin_amdgcn_s_setprio(0);
        // ---- causal mask (tiles overlapping the wave's diagonal band)
        if (ks0 + 63 > wrow0) {
#pragma unroll
            for (int g = 0; g < 2; g++) {
                int qrow = wrow0 + g * 16 + l15;
#pragma unroll
                for (int nt = 0; nt < 4; nt++)
#pragma unroll
                    for (int r = 0; r < 4; r++)
                        if (ks0 + nt * 16 + quad * 4 + r > qrow)
                            sc[g][nt][r] = NEG_INF;
            }
        }
        // ---- row max (reduced over quads; row-uniform)
        float mx[2];
#pragma unroll
        for (int g = 0; g < 2; g++) {
            float m = NEG_INF;
#pragma unroll
            for (int nt = 0; nt < 4; nt++)
#pragma unroll
                for (int r = 0; r < 4; r++) m = fmaxf(m, sc[g][nt][r]);
            m = fmaxf(m, __shfl_xor(m, 16));
            m = fmaxf(m, __shfl_xor(m, 32));
            mx[g] = m;
        }
        // ---- defer-max: rescale only when max grew by >8 (log2 domain)
        int need = (mx[0] > m_r[0] + 8.f) || (mx[1] > m_r[1] + 8.f);
        if (__any(need)) {
#pragma unroll
            for (int g = 0; g < 2; g++) {
                float mn = fmaxf(m_r[g], mx[g]);
                float a = __builtin_amdgcn_exp2f(m_r[g] - mn);
                m_r[g] = mn;
                l_r[g] *= a;
#pragma unroll
                for (int dt = 0; dt < 4; dt++)
#pragma unroll
                    for (int r = 0; r < 4; r++) o[dt][g][r] *= a;
            }
        }
        // ---- P = exp2(S - m); per-lane partial sums only (no shuffles)
#pragma unroll
        for (int g = 0; g < 2; g++) {
            float s = 0.f;
#pragma unroll
            for (int nt = 0; nt < 4; nt++)
#pragma unroll
                for (int r = 0; r < 4; r++) {
                    sc[g][nt][r] = __builtin_amdgcn_exp2f(sc[g][nt][r] - m_r[g]);
                    s += sc[g][nt][r];
                }
            l_r[g] += s;
        }
        // ---- P^T -> LDS: packed 8B writes ([qrow][key], keys quad*4+r contig)
#pragma unroll
        for (int g = 0; g < 2; g++)
#pragma unroll
            for (int nt = 0; nt < 4; nt++) {
                bf16x4 pk;
#pragma unroll
                for (int r = 0; r < 4; r++) pk[r] = (bf16)sc[g][nt][r];
                *(bf16x4*)&pw[(g * 16 + l15) * 72 + nt * 16 + quad * 4] = pk;
            }
        // ---- P^T B-frags: B[k=key=quad*8+j+32c][n=qrow=l15]
        bf16x8 bp[2][2];
#pragma unroll
        for (int g = 0; g < 2; g++) {
            bp[g][0] = *(const bf16x8*)&pw[(g * 16 + l15) * 72 + quad * 8];
            bp[g][1] = *(const bf16x8*)&pw[(g * 16 + l15) * 72 + 32 + quad * 8];
        }
        // ---- accumulate O^T += V^T·P^T (no per-tile rescale: deferred)
        __builtin_amdgcn_s_setprio(1);
#pragma unroll
        for (int dt = 0; dt < 4; dt++) {
            bf16x8 av0 = *(const bf16x8*)&vtb[(dt * 16 + l15) * 72 + quad * 8];
            bf16x8 av1 = *(const bf16x8*)&vtb[(dt * 16 + l15) * 72 + 32 + quad * 8];
#pragma unroll
            for (int g = 0; g < 2; g++) {
                o[dt][g] = MFMA_16x16x32(av0, bp[g][0], o[dt][g]);
                o[dt][g] = MFMA_16x16x32(av1, bp[g][1], o[dt][g]);
            }
        }
        __builtin_amdgcn_s_setprio(0);
    }

    // ---- epilogue: reduce l over quads, then scale + store
    const int b = bh >> 4, h = bh & 15;
#pragma unroll
    for (int g = 0; g < 2; g++) {
        float l = l_r[g];
        l += __shfl_xor(l, 16);
        l += __shfl_xor(l, 32);
        float rl = 1.f / l;
        int row = wrow0 + g * 16 + l15;
#pragma unroll
        for (int dt = 0; dt < 4; dt++) {
            bf16x4 ov;
#pragma unroll
            for (int r = 0; r < 4; r++) ov[r] = (bf16)(o[dt][g][r] * rl);
            *(bf16x4*)&Ob[((size_t)b * CS + row) * CD + h * 64 + dt * 16 + quad * 4] = ov;
        }
    }
}

// ---------------------------------------------------------------------------
extern "C" void kernel_launch(void* const* d_in, const int* in_sizes, int n_in,
                              void* d_out, int out_size, void* d_ws, size_t ws_size,
                              hipStream_t stream) {
    const float* x  = (const float*)d_in[0];
    const float* Wq = (const float*)d_in[1];
    const float* bq = (const float*)d_in[2];
    const float* Wk = (const float*)d_in[3];
    const float* bk = (const float*)d_in[4];
    const float* Wv = (const float*)d_in[5];
    const float* bv = (const float*)d_in[6];
    const float* Wo = (const float*)d_in[7];
    const float* bo = (const float*)d_in[8];
    float* out = (float*)d_out;

    // workspace (bf16 elems): xb[4M] Wt[4*1M] Qb[4M] Kb[4M] Vb[4M] Ob[4M]
    bf16* xb = (bf16*)d_ws;
    bf16* Wt = xb + (size_t)CM * CD;
    bf16* Qb = Wt + (size_t)4 * CD * CD;
    bf16* Kb = Qb + (size_t)CB * CH * CS * 64;
    bf16* Vb = Kb + (size_t)CB * CH * CS * 64;
    bf16* Ob = Vb + (size_t)CB * CH * CS * 64;

    conv_x<<<(CM * CD) / (256 * 8), 256, 0, stream>>>(x, xb);
    conv_wt<<<dim3(CD / 64, CD / 64, 4), 256, 0, stream>>>(Wq, Wk, Wv, Wo, Wt);

    gemm_qkv<<<dim3(24, CM / 128), 256, 0, stream>>>(
        xb, Wt, bq, bk, bv, Qb, Kb, Vb);

    // 512 blocks = 32 bh x 16 q-blocks (128 rows each), long halves first
    attn_kernel<<<512, 256, 0, stream>>>(Qb, Kb, Vb, Ob);

    gemm_o<<<dim3(8, CM / 64), 256, 0, stream>>>(
        Ob, Wt + (size_t)3 * CD * CD, bo, out);
}

// Round 3
// 181.798 us; speedup vs baseline: 1.0625x; 1.0543x over previous
//
#include <hip/hip_runtime.h>
#include <hip/hip_bf16.h>

typedef __bf16 bf16;
typedef __bf16 bf16x4 __attribute__((ext_vector_type(4)));
typedef __bf16 bf16x8 __attribute__((ext_vector_type(8)));
typedef float floatx4 __attribute__((ext_vector_type(4)));

#define MFMA_16x16x32(a, b, c) __builtin_amdgcn_mfma_f32_16x16x32_bf16((a), (b), (c), 0, 0, 0)
#define NEG_INF (-__builtin_inff())

// Problem constants (B=2, S=2048, D=1024, H=16, d=64)
#define CB 2
#define CS 2048
#define CD 1024
#define CH 16
#define CM (CB * CS)
// Q prescale: DIM^-0.5 * log2(e)  (softmax done in base-2 domain)
#define QSC (0.03125f * 1.44269504088896340736f)

// async global->LDS, 16B per lane; LDS dest = wave-uniform base + lane*16
__device__ __forceinline__ void async16(const bf16* g, bf16* l) {
    __builtin_amdgcn_global_load_lds(
        (const __attribute__((address_space(1))) void*)g,
        (__attribute__((address_space(3))) void*)l, 16, 0, 0);
}

// ---------------------------------------------------------------------------
// Prep: x fp32 -> bf16
// ---------------------------------------------------------------------------
__global__ __launch_bounds__(256) void conv_x(const float* __restrict__ x,
                                              bf16* __restrict__ xb) {
    size_t i = ((size_t)blockIdx.x * 256 + threadIdx.x) * 8;
    float4 a = *(const float4*)(x + i);
    float4 b = *(const float4*)(x + i + 4);
    bf16x8 v;
    v[0] = (bf16)a.x; v[1] = (bf16)a.y; v[2] = (bf16)a.z; v[3] = (bf16)a.w;
    v[4] = (bf16)b.x; v[5] = (bf16)b.y; v[6] = (bf16)b.z; v[7] = (bf16)b.w;
    *(bf16x8*)(xb + i) = v;
}

// ---------------------------------------------------------------------------
// Prep: W [K][N] fp32 -> Wt [N][K] bf16 (64x64 LDS tile transpose)
// grid: (N/64, K/64, 4)  — z selects which W
// ---------------------------------------------------------------------------
__global__ __launch_bounds__(256) void conv_wt(
    const float* __restrict__ W0, const float* __restrict__ W1,
    const float* __restrict__ W2, const float* __restrict__ W3,
    bf16* __restrict__ Wt) {
    __shared__ bf16 Ws[64 * 68];
    const float* W = blockIdx.z == 0 ? W0 : blockIdx.z == 1 ? W1
                   : blockIdx.z == 2 ? W2 : W3;
    bf16* out = Wt + (size_t)blockIdx.z * CD * CD;
    const int t = threadIdx.x;
    const int n0 = blockIdx.x * 64, k0 = blockIdx.y * 64;
    const int rr = t >> 4, c4 = (t & 15) * 4;
#pragma unroll
    for (int i = 0; i < 4; i++) {
        int r = rr + i * 16;
        float4 f = *(const float4*)(W + (size_t)(k0 + r) * CD + n0 + c4);
        bf16x4 v;
        v[0] = (bf16)f.x; v[1] = (bf16)f.y; v[2] = (bf16)f.z; v[3] = (bf16)f.w;
        *(bf16x4*)&Ws[r * 68 + c4] = v;
    }
    __syncthreads();
#pragma unroll
    for (int i = 0; i < 4; i++) {
        int n = rr + i * 16;
        bf16x4 v;
#pragma unroll
        for (int j = 0; j < 4; j++) v[j] = Ws[(c4 + j) * 68 + n];
        *(bf16x4*)(out + (size_t)(n0 + n) * CD + k0 + c4) = v;
    }
}

// ---------------------------------------------------------------------------
// Fused QKV GEMM (m97 structure): 128x128 tile, BK=32, global_load_lds x16B.
// which = blockIdx.x>>3: 0->Q (scaled by QSC, [bh][S][64]), 1->K ([bh][S][64]),
// 2->V (transposed store [bh][64][S], packed bf16x4 along tokens).
// ---------------------------------------------------------------------------
__global__ __launch_bounds__(256) void gemm_qkv(
    const bf16* __restrict__ A, const bf16* __restrict__ Bt,
    const float* __restrict__ bq, const float* __restrict__ bk,
    const float* __restrict__ bv,
    bf16* __restrict__ Qb, bf16* __restrict__ Kb, bf16* __restrict__ Vb) {
    __shared__ bf16 As[128 * 32];
    __shared__ bf16 Bs[128 * 32];
    const int t = threadIdx.x, w = t >> 6, lane = t & 63;
    const int quad = lane >> 4, l15 = lane & 15;
    const int which = blockIdx.x >> 3;
    const int bn = (blockIdx.x & 7) * 128, bm = blockIdx.y * 128;
    const bf16* Bw = Bt + (size_t)which * CD * CD;

    const bf16* ag = A + (size_t)(bm + w * 16 + (lane >> 2)) * CD + (lane & 3) * 8;
    const bf16* bg = Bw + (size_t)(bn + w * 16 + (lane >> 2)) * CD + (lane & 3) * 8;
    const int lo = w * 16 * 32;   // wave-uniform LDS chunk base

    const int wm = (w >> 1) * 64, wn = (w & 1) * 64;
    floatx4 acc[4][4] = {};

    for (int k0 = 0; k0 < CD; k0 += 32) {
        async16(ag + k0, &As[lo]);
        async16(ag + (size_t)64 * CD + k0, &As[lo + 64 * 32]);
        async16(bg + k0, &Bs[lo]);
        async16(bg + (size_t)64 * CD + k0, &Bs[lo + 64 * 32]);
        __syncthreads();
        bf16x8 af[4], bfr[4];
#pragma unroll
        for (int mt = 0; mt < 4; mt++)
            af[mt] = *(const bf16x8*)&As[(wm + mt * 16 + l15) * 32 + quad * 8];
#pragma unroll
        for (int nt = 0; nt < 4; nt++)
            bfr[nt] = *(const bf16x8*)&Bs[(wn + nt * 16 + l15) * 32 + quad * 8];
#pragma unroll
        for (int mt = 0; mt < 4; mt++)
#pragma unroll
            for (int nt = 0; nt < 4; nt++)
                acc[mt][nt] = MFMA_16x16x32(af[mt], bfr[nt], acc[mt][nt]);
        __syncthreads();
    }

    const float* bias = which == 0 ? bq : which == 1 ? bk : bv;
    bf16* out = which == 0 ? Qb : Kb;
#pragma unroll
    for (int mt = 0; mt < 4; mt++) {
#pragma unroll
        for (int nt = 0; nt < 4; nt++) {
            int token = bm + wm + mt * 16 + quad * 4;      // 4 consecutive tokens
            int col = bn + wn + nt * 16 + l15;             // feature
            int b = token >> 11, s = token & (CS - 1);
            int h = col >> 6, dd = col & 63;
            if (which == 2) {
                // V^T [bh][d][S]: 4 tokens contiguous -> packed 8B store
                bf16x4 pv;
#pragma unroll
                for (int r = 0; r < 4; r++) pv[r] = (bf16)(acc[mt][nt][r] + bias[col]);
                *(bf16x4*)&Vb[(((size_t)(b * CH + h)) * 64 + dd) * CS + s] = pv;
            } else {
#pragma unroll
                for (int r = 0; r < 4; r++) {
                    float v = acc[mt][nt][r] + bias[col];
                    if (which == 0) v *= QSC;
                    out[(((size_t)(b * CH + h)) * CS + s + r) * 64 + dd] = (bf16)v;
                }
            }
        }
    }
}

// ---------------------------------------------------------------------------
// O-projection GEMM: 64x128 tile, fp32 output. grid: (8, M/64).
// ---------------------------------------------------------------------------
__global__ __launch_bounds__(256) void gemm_o(
    const bf16* __restrict__ A, const bf16* __restrict__ Bt,
    const float* __restrict__ bias, float* __restrict__ out) {
    __shared__ bf16 As[64 * 32];
    __shared__ bf16 Bs[128 * 32];
    const int t = threadIdx.x, w = t >> 6, lane = t & 63;
    const int quad = lane >> 4, l15 = lane & 15;
    const int bn = blockIdx.x * 128, bm = blockIdx.y * 64;

    const bf16* ag = A + (size_t)(bm + w * 16 + (lane >> 2)) * CD + (lane & 3) * 8;
    const bf16* bg = Bt + (size_t)(bn + w * 16 + (lane >> 2)) * CD + (lane & 3) * 8;
    const int lo = w * 16 * 32;

    const int wm = (w >> 1) * 32, wn = (w & 1) * 64;
    floatx4 acc[2][4] = {};

    for (int k0 = 0; k0 < CD; k0 += 32) {
        async16(ag + k0, &As[lo]);
        async16(bg + k0, &Bs[lo]);
        async16(bg + (size_t)64 * CD + k0, &Bs[lo + 64 * 32]);
        __syncthreads();
        bf16x8 af[2], bfr[4];
#pragma unroll
        for (int mt = 0; mt < 2; mt++)
            af[mt] = *(const bf16x8*)&As[(wm + mt * 16 + l15) * 32 + quad * 8];
#pragma unroll
        for (int nt = 0; nt < 4; nt++)
            bfr[nt] = *(const bf16x8*)&Bs[(wn + nt * 16 + l15) * 32 + quad * 8];
#pragma unroll
        for (int mt = 0; mt < 2; mt++)
#pragma unroll
            for (int nt = 0; nt < 4; nt++)
                acc[mt][nt] = MFMA_16x16x32(af[mt], bfr[nt], acc[mt][nt]);
        __syncthreads();
    }

#pragma unroll
    for (int mt = 0; mt < 2; mt++)
#pragma unroll
        for (int nt = 0; nt < 4; nt++)
#pragma unroll
            for (int r = 0; r < 4; r++) {
                int row = bm + wm + mt * 16 + quad * 4 + r;
                int col = bn + wn + nt * 16 + l15;
                out[(size_t)row * CD + col] = acc[mt][nt][r] + bias[col];
            }
}

// ---------------------------------------------------------------------------
// Flash attention v7 (resubmission — R2 bench was an infra failure, no
// counters; kernel audited for deadlock/OOB/NaN: none found; 108 KB static
// LDS is within gfx950 precedent).
// In-block split-K over key tiles: 512 threads = 8 waves = 2 groups of 4
// waves over the SAME 128 q-rows. Group g processes key tiles g, g+2, ...
// (nT = 2qb+2 is even -> exact halves), each group with its own
// double-buffered K/V LDS; one barrier per step shared by both groups.
// Partial (m, l, O) merged via LDS in the epilogue. Critical path per block
// halves vs v6; 2 waves/SIMD sustained within a single block.
// Grid 512 = qb descending (LPT) x 32 bh.
// ---------------------------------------------------------------------------
__global__ __launch_bounds__(512) void attn_kernel(
    const bf16* __restrict__ Q, const bf16* __restrict__ Kg,
    const bf16* __restrict__ Vg, bf16* __restrict__ Ob) {
    __shared__ bf16 Ks[2][2][64 * 72];   // [grp][buf][key][dim]
    __shared__ bf16 Vt[2][2][64 * 72];   // [grp][buf][dim][key]
    __shared__ bf16 Pt[8][32 * 72];      // per-wave P^T as [qrow][key]

    const int t = threadIdx.x;
    const int w = t >> 6, lane = t & 63;
    const int grp = w >> 2, wg = w & 3;      // key-split group, wave-in-group
    const int quad = lane >> 4, l15 = lane & 15;

    const int qb = 15 - (blockIdx.x >> 5);   // q-block, longest first (LPT)
    const int bh = blockIdx.x & 31;          // B*H = 32
    const int q0 = qb * 128;
    const int wrow0 = q0 + wg * 32;          // this wave's first qrow
    const int nT = 2 * qb + 2;               // 64-key tiles (even, >= 2)
    const int nS = nT >> 1;                  // steps per group

    const bf16* Qh = Q + (size_t)bh * CS * 64;
    const bf16* Kh = Kg + (size_t)bh * CS * 64;
    const bf16* Vh = Vg + (size_t)bh * 64 * CS;

    // staging map (within 256-thread group): 16B x2 of one K row / V^T row
    const int tl = t & 255;
    const int strow = tl >> 2, soff = (tl & 3) * 16;
    const bf16* ksrc = Kh + (size_t)strow * 64 + soff;   // + tile*64*64
    const bf16* vsrc = Vh + (size_t)strow * CS + soff;   // + tile*64
    const int sbase = strow * 72 + soff;

    // ---- prologue: tile (grp) -> LDS buf0; tile (grp+2) -> regs
    {
        const bf16* k0p = ksrc + (size_t)grp * 64 * 64;
        const bf16* v0p = vsrc + grp * 64;
        bf16x8 a = *(const bf16x8*)k0p, b = *(const bf16x8*)(k0p + 8);
        bf16x8 c = *(const bf16x8*)v0p, d = *(const bf16x8*)(v0p + 8);
        *(bf16x8*)&Ks[grp][0][sbase]     = a;
        *(bf16x8*)&Ks[grp][0][sbase + 8] = b;
        *(bf16x8*)&Vt[grp][0][sbase]     = c;
        *(bf16x8*)&Vt[grp][0][sbase + 8] = d;
    }
    bf16x8 kr0, kr1, vr0, vr1;
    {
        int t1 = (grp + 2 < nT) ? grp + 2 : 0;
        const bf16* kn = ksrc + (size_t)t1 * 64 * 64;
        const bf16* vn = vsrc + t1 * 64;
        kr0 = *(const bf16x8*)kn;  kr1 = *(const bf16x8*)(kn + 8);
        vr0 = *(const bf16x8*)vn;  vr1 = *(const bf16x8*)(vn + 8);
    }

    // ---- Q fragments (B-operand of S^T): Q[qrow=g*16+l15][dim=quad*8+j+32c]
    bf16x8 qf[2][2];
#pragma unroll
    for (int g = 0; g < 2; g++) {
        const bf16* qsrc = Qh + (size_t)(wrow0 + g * 16 + l15) * 64 + quad * 8;
        qf[g][0] = *(const bf16x8*)qsrc;
        qf[g][1] = *(const bf16x8*)(qsrc + 32);
    }

    floatx4 o[4][2] = {};        // O^T: [dim-subtile][qrow-group]
    float m_r[2] = {NEG_INF, NEG_INF};
    float l_r[2] = {0.f, 0.f};   // per-lane partial row-sums

    bf16* pw = Pt[w];

    for (int s = 0; s < nS; s++) {
        const int tile = 2 * s + grp;
        const int cur = s & 1;
        const int ks0 = tile * 64;
        __syncthreads();   // buf[cur] staged; buf[cur^1] readers done (s-1)

        // ---- stage tile+2 into the other buffer (regs loaded last step)
        *(bf16x8*)&Ks[grp][cur ^ 1][sbase]     = kr0;
        *(bf16x8*)&Ks[grp][cur ^ 1][sbase + 8] = kr1;
        *(bf16x8*)&Vt[grp][cur ^ 1][sbase]     = vr0;
        *(bf16x8*)&Vt[grp][cur ^ 1][sbase + 8] = vr1;
        // ---- issue global loads for tile+4
        {
            int nk = (tile + 4 < nT) ? tile + 4 : 0;
            const bf16* kn = ksrc + (size_t)nk * 64 * 64;
            const bf16* vn = vsrc + nk * 64;
            kr0 = *(const bf16x8*)kn;  kr1 = *(const bf16x8*)(kn + 8);
            vr0 = *(const bf16x8*)vn;  vr1 = *(const bf16x8*)(vn + 8);
        }
        // waves whose rows are all below this key tile skip compute
        if (ks0 > wrow0 + 31) continue;

        const bf16* ksb = Ks[grp][cur];
        const bf16* vtb = Vt[grp][cur];

        // ---- S^T = K·Q^T: lane holds S^T[key=nt*16+quad*4+r][qrow=g*16+l15]
        floatx4 sc[2][4] = {};
        __builtin_amdgcn_s_setprio(1);
#pragma unroll
        for (int nt = 0; nt < 4; nt++) {
            bf16x8 af0 = *(const bf16x8*)&ksb[(nt * 16 + l15) * 72 + quad * 8];
            bf16x8 af1 = *(const bf16x8*)&ksb[(nt * 16 + l15) * 72 + 32 + quad * 8];
#pragma unroll
            for (int g = 0; g < 2; g++) {
                sc[g][nt] = MFMA_16x16x32(af0, qf[g][0], sc[g][nt]);
                sc[g][nt] = MFMA_16x16x32(af1, qf[g][1], sc[g][nt]);
            }
        }
        __builtin_amdgcn_s_setprio(0);
        // ---- causal mask (tiles overlapping the wave's diagonal band)
        if (ks0 + 63 > wrow0) {
#pragma unroll
            for (int g = 0; g < 2; g++) {
                int qrow = wrow0 + g * 16 + l15;
#pragma unroll
                for (int nt = 0; nt < 4; nt++)
#pragma unroll
                    for (int r = 0; r < 4; r++)
                        if (ks0 + nt * 16 + quad * 4 + r > qrow)
                            sc[g][nt][r] = NEG_INF;
            }
        }
        // ---- row max (tree-reduced; then quad-reduced via 2 shuffles)
        float mx[2];
#pragma unroll
        for (int g = 0; g < 2; g++) {
            floatx4 v01, v23, vm;
#pragma unroll
            for (int c = 0; c < 4; c++) {
                v01[c] = fmaxf(sc[g][0][c], sc[g][1][c]);
                v23[c] = fmaxf(sc[g][2][c], sc[g][3][c]);
                vm[c] = fmaxf(v01[c], v23[c]);
            }
            float m = fmaxf(fmaxf(vm[0], vm[1]), fmaxf(vm[2], vm[3]));
            m = fmaxf(m, __shfl_xor(m, 16));
            m = fmaxf(m, __shfl_xor(m, 32));
            mx[g] = m;
        }
        // ---- defer-max: rescale only when max grew by >8 (log2 domain)
        int need = (mx[0] > m_r[0] + 8.f) || (mx[1] > m_r[1] + 8.f);
        if (__any(need)) {
#pragma unroll
            for (int g = 0; g < 2; g++) {
                float mn = fmaxf(m_r[g], mx[g]);
                float a = __builtin_amdgcn_exp2f(m_r[g] - mn);
                m_r[g] = mn;
                l_r[g] *= a;
#pragma unroll
                for (int dt = 0; dt < 4; dt++)
#pragma unroll
                    for (int r = 0; r < 4; r++) o[dt][g][r] *= a;
            }
        }
        // ---- P = exp2(S - m); per-lane partial sums (tree)
#pragma unroll
        for (int g = 0; g < 2; g++) {
#pragma unroll
            for (int nt = 0; nt < 4; nt++)
#pragma unroll
                for (int r = 0; r < 4; r++)
                    sc[g][nt][r] = __builtin_amdgcn_exp2f(sc[g][nt][r] - m_r[g]);
            floatx4 st = (sc[g][0] + sc[g][1]) + (sc[g][2] + sc[g][3]);
            l_r[g] += (st[0] + st[1]) + (st[2] + st[3]);
        }
        // ---- P^T -> LDS: packed 8B writes ([qrow][key], keys quad*4+r contig)
#pragma unroll
        for (int g = 0; g < 2; g++)
#pragma unroll
            for (int nt = 0; nt < 4; nt++) {
                bf16x4 pk;
#pragma unroll
                for (int r = 0; r < 4; r++) pk[r] = (bf16)sc[g][nt][r];
                *(bf16x4*)&pw[(g * 16 + l15) * 72 + nt * 16 + quad * 4] = pk;
            }
        // ---- P^T B-frags: B[k=key=quad*8+j+32c][n=qrow=l15]
        bf16x8 bp[2][2];
#pragma unroll
        for (int g = 0; g < 2; g++) {
            bp[g][0] = *(const bf16x8*)&pw[(g * 16 + l15) * 72 + quad * 8];
            bp[g][1] = *(const bf16x8*)&pw[(g * 16 + l15) * 72 + 32 + quad * 8];
        }
        // ---- accumulate O^T += V^T·P^T
        __builtin_amdgcn_s_setprio(1);
#pragma unroll
        for (int dt = 0; dt < 4; dt++) {
            bf16x8 av0 = *(const bf16x8*)&vtb[(dt * 16 + l15) * 72 + quad * 8];
            bf16x8 av1 = *(const bf16x8*)&vtb[(dt * 16 + l15) * 72 + 32 + quad * 8];
#pragma unroll
            for (int g = 0; g < 2; g++) {
                o[dt][g] = MFMA_16x16x32(av0, bp[g][0], o[dt][g]);
                o[dt][g] = MFMA_16x16x32(av1, bp[g][1], o[dt][g]);
            }
        }
        __builtin_amdgcn_s_setprio(0);
    }

    // ---- merge group partials via LDS (reuse Ks region: 36864B exactly)
    __syncthreads();                       // all K/V/P reads done
    float* mg = (float*)&Ks[0][0][0];
    float* base = mg + (size_t)(wg * 64 + lane) * 36;   // 32 o + 2 m + 2 l
    if (grp == 1) {
#pragma unroll
        for (int dt = 0; dt < 4; dt++)
#pragma unroll
            for (int g = 0; g < 2; g++)
                *(floatx4*)(base + (dt * 2 + g) * 4) = o[dt][g];
        base[32] = m_r[0]; base[33] = m_r[1];
        base[34] = l_r[0]; base[35] = l_r[1];
    }
    __syncthreads();
    if (grp == 0) {
        float a0[2], a1[2];
#pragma unroll
        for (int g = 0; g < 2; g++) {
            float m1 = base[32 + g], l1 = base[34 + g];
            float mm = fmaxf(m_r[g], m1);          // m_r[g] finite (tile 0)
            a0[g] = __builtin_amdgcn_exp2f(m_r[g] - mm);
            a1[g] = __builtin_amdgcn_exp2f(m1 - mm);
            l_r[g] = l_r[g] * a0[g] + l1 * a1[g];
        }
#pragma unroll
        for (int dt = 0; dt < 4; dt++)
#pragma unroll
            for (int g = 0; g < 2; g++) {
                floatx4 o1 = *(const floatx4*)(base + (dt * 2 + g) * 4);
#pragma unroll
                for (int r = 0; r < 4; r++)
                    o[dt][g][r] = o[dt][g][r] * a0[g] + o1[r] * a1[g];
            }
        // ---- epilogue: reduce l over quads, then scale + store
        const int b = bh >> 4, h = bh & 15;
#pragma unroll
        for (int g = 0; g < 2; g++) {
            float l = l_r[g];
            l += __shfl_xor(l, 16);
            l += __shfl_xor(l, 32);
            float rl = 1.f / l;
            int row = wrow0 + g * 16 + l15;
#pragma unroll
            for (int dt = 0; dt < 4; dt++) {
                bf16x4 ov;
#pragma unroll
                for (int r = 0; r < 4; r++) ov[r] = (bf16)(o[dt][g][r] * rl);
                *(bf16x4*)&Ob[((size_t)b * CS + row) * CD + h * 64 + dt * 16 + quad * 4] = ov;
            }
        }
    }
}

// ---------------------------------------------------------------------------
extern "C" void kernel_launch(void* const* d_in, const int* in_sizes, int n_in,
                              void* d_out, int out_size, void* d_ws, size_t ws_size,
                              hipStream_t stream) {
    const float* x  = (const float*)d_in[0];
    const float* Wq = (const float*)d_in[1];
    const float* bq = (const float*)d_in[2];
    const float* Wk = (const float*)d_in[3];
    const float* bk = (const float*)d_in[4];
    const float* Wv = (const float*)d_in[5];
    const float* bv = (const float*)d_in[6];
    const float* Wo = (const float*)d_in[7];
    const float* bo = (const float*)d_in[8];
    float* out = (float*)d_out;

    // workspace (bf16 elems): xb[4M] Wt[4*1M] Qb[4M] Kb[4M] Vb[4M] Ob[4M]
    bf16* xb = (bf16*)d_ws;
    bf16* Wt = xb + (size_t)CM * CD;
    bf16* Qb = Wt + (size_t)4 * CD * CD;
    bf16* Kb = Qb + (size_t)CB * CH * CS * 64;
    bf16* Vb = Kb + (size_t)CB * CH * CS * 64;
    bf16* Ob = Vb + (size_t)CB * CH * CS * 64;

    conv_x<<<(CM * CD) / (256 * 8), 256, 0, stream>>>(x, xb);
    conv_wt<<<dim3(CD / 64, CD / 64, 4), 256, 0, stream>>>(Wq, Wk, Wv, Wo, Wt);

    gemm_qkv<<<dim3(24, CM / 128), 256, 0, stream>>>(
        xb, Wt, bq, bk, bv, Qb, Kb, Vb);

    // 512 blocks = 16 q-blocks (longest first, LPT) x 32 bh; 512 thr each
    attn_kernel<<<512, 512, 0, stream>>>(Qb, Kb, Vb, Ob);

    gemm_o<<<dim3(8, CM / 64), 256, 0, stream>>>(
        Ob, Wt + (size_t)3 * CD * CD, bo, out);
}